// Round 8
// baseline (767.280 us; speedup 1.0000x reference)
//
#include <hip/hip_runtime.h>

typedef _Float16 half8_t __attribute__((ext_vector_type(8)));
typedef _Float16 half4_t __attribute__((ext_vector_type(4)));

#define NU 100000
#define NI 50000
#define NR (NU + NI)          // unified rows: users then items
#define D 64
#define COARSE 1024
#define RPB 147               // rows per coarse bucket (147*1024 = 150528 >= NR)
#define CAP 8800              // csr LDS staging capacity (bucket mean 6250, sigma ~79)
#define CHUNK 6144            // placements per block in count/place (fits LDS staging)
#define RPT 6                 // records per thread (CHUNK / 1024)
#define NT4 (NR * 16)         // float4 count of full table

// out = concat(ue, ie) fp32; curh = same data fp16
__global__ void init_kernel(const float4* __restrict__ ue, const float4* __restrict__ ie,
                            float4* __restrict__ out, half4_t* __restrict__ curh) {
    int idx = blockIdx.x * 256 + threadIdx.x;
    if (idx >= NT4) return;
    float4 v = (idx < NU * 16) ? ue[idx] : ie[idx - NU * 16];
    out[idx] = v;
    half4_t h;
    h[0] = (_Float16)v.x; h[1] = (_Float16)v.y; h[2] = (_Float16)v.z; h[3] = (_Float16)v.w;
    curh[idx] = h;
}

// placement p -> dest row (unified row space, items offset by NU)
__device__ __forceinline__ int place_dest(int p, const int* ui_r, const int* ui_c,
                                          const int* uu_r, const int* ii_r,
                                          int n_ui, int n_uu) {
    if (p < 2 * n_ui) {
        int e = p >> 1;
        return (p & 1) ? NU + ui_c[e] : ui_r[e];
    } else if (p < 2 * n_ui + n_uu) {
        return uu_r[p - 2 * n_ui];
    } else {
        return NU + ii_r[p - 2 * n_ui - n_uu];
    }
}

// per-block coarse histogram -> m[block][COARSE]
__global__ void count_kernel(const int* __restrict__ ui_r, const int* __restrict__ ui_c,
                             const int* __restrict__ uu_r, const int* __restrict__ ii_r,
                             int* __restrict__ m, int n_ui, int n_uu, int nnzt) {
    __shared__ int cnt[COARSE];
    int tid = threadIdx.x;
    cnt[tid] = 0;
    __syncthreads();
    int blk0 = blockIdx.x * CHUNK;
#pragma unroll
    for (int k = 0; k < RPT; k++) {
        int p = blk0 + k * 1024 + tid;
        if (p < nnzt) {
            int dest = place_dest(p, ui_r, ui_c, uu_r, ii_r, n_ui, n_uu);
            atomicAdd(&cnt[dest / RPB], 1);
        }
    }
    __syncthreads();
    m[blockIdx.x * COARSE + tid] = cnt[tid];
}

// column sums of m -> tots[COARSE]  (8 blocks x 128 threads, coalesced)
__global__ void colsum_kernel(const int* __restrict__ m, int* __restrict__ tots, int nblk) {
    int c = blockIdx.x * 128 + threadIdx.x;
    int tot = 0;
    for (int b = 0; b < nblk; b++) tot += m[b * COARSE + c];
    tots[c] = tot;
}

// single block: exclusive scan of tots -> coarse_base; set ptr[NR]
__global__ void scan1_kernel(const int* __restrict__ tots, int* __restrict__ coarse_base,
                             int* __restrict__ ptr_nr) {
    __shared__ int s[COARSE];
    int tid = threadIdx.x;
    int x = tots[tid];
    s[tid] = x;
    __syncthreads();
    for (int off = 1; off < COARSE; off <<= 1) {
        int t = (tid >= off) ? s[tid - off] : 0;
        __syncthreads();
        s[tid] += t;
        __syncthreads();
    }
    coarse_base[tid] = s[tid] - x;
    if (tid == COARSE - 1) {
        coarse_base[COARSE] = s[tid];
        *ptr_nr = s[tid];
    }
}

// rewrite m in place as absolute per-(block,bucket) base offsets
__global__ void rebase_kernel(int* __restrict__ m, const int* __restrict__ coarse_base, int nblk) {
    int c = blockIdx.x * 128 + threadIdx.x;
    int run = coarse_base[c];
    for (int b = 0; b < nblk; b++) {
        int v = m[b * COARSE + c];
        m[b * COARSE + c] = run;
        run += v;
    }
}

// LDS-staged bucket sort per block -> fully coalesced scratch writeout.
// record: x = dl<<18 | src ; y = (c<<16) | val_fp16  (csr truncates y to 16 bits)
__global__ void place_kernel(const int* __restrict__ ui_r, const int* __restrict__ ui_c,
                             const float* __restrict__ ui_v,
                             const int* __restrict__ uu_r, const int* __restrict__ uu_c,
                             const float* __restrict__ uu_v,
                             const int* __restrict__ ii_r, const int* __restrict__ ii_c,
                             const float* __restrict__ ii_v,
                             const int* __restrict__ m, uint2* __restrict__ scratch,
                             int n_ui, int n_uu, int nnzt) {
    __shared__ uint2 rec[CHUNK];      // 48 KB
    __shared__ int cnt[COARSE];       // 4 KB
    __shared__ int lbase[COARSE];     // 4 KB
    __shared__ int base_s[COARSE];    // 4 KB
    __shared__ int s_ntot;
    int tid = threadIdx.x;
    cnt[tid] = 0;
    __syncthreads();
    int blk0 = blockIdx.x * CHUNK;
    int rk[RPT];
#pragma unroll
    for (int k = 0; k < RPT; k++) {
        int p = blk0 + k * 1024 + tid;
        rk[k] = -1;
        if (p < nnzt) {
            int dest = place_dest(p, ui_r, ui_c, uu_r, ii_r, n_ui, n_uu);
            int c = dest / RPB;
            int lr = atomicAdd(&cnt[c], 1);   // < 6144 -> 14 bits
            rk[k] = (c << 14) | lr;
        }
    }
    __syncthreads();
    // exclusive scan of cnt -> lbase
    int own = cnt[tid];
    lbase[tid] = own;
    __syncthreads();
    for (int off = 1; off < COARSE; off <<= 1) {
        int t = (tid >= off) ? lbase[tid - off] : 0;
        __syncthreads();
        lbase[tid] += t;
        __syncthreads();
    }
    int incl = lbase[tid];
    __syncthreads();
    lbase[tid] = incl - own;
    if (tid == COARSE - 1) s_ntot = incl;
    base_s[tid] = m[blockIdx.x * COARSE + tid];
    __syncthreads();
    // phase 2: decode records, scatter into LDS grouped by bucket
#pragma unroll
    for (int k = 0; k < RPT; k++) {
        int p = blk0 + k * 1024 + tid;
        if (p >= nnzt) continue;
        int dest, src;
        float v;
        if (p < 2 * n_ui) {
            int e = p >> 1;
            int r = ui_r[e], cc = ui_c[e];
            v = ui_v[e];
            if (p & 1) { dest = NU + cc; src = r; }
            else       { dest = r; src = NU + cc; }
        } else if (p < 2 * n_ui + n_uu) {
            int e = p - 2 * n_ui;
            dest = uu_r[e]; src = uu_c[e]; v = uu_v[e];
        } else {
            int e = p - 2 * n_ui - n_uu;
            dest = NU + ii_r[e]; src = NU + ii_c[e]; v = ii_v[e];
        }
        int c  = rk[k] >> 14;
        int lr = rk[k] & 0x3FFF;
        int dl = dest - c * RPB;                  // < 147
        _Float16 hv = (_Float16)v;
        unsigned short us;
        __builtin_memcpy(&us, &hv, 2);
        rec[lbase[c] + lr] = make_uint2(((unsigned)dl << 18) | (unsigned)src,
                                        ((unsigned)c << 16) | (unsigned)us);
    }
    __syncthreads();
    // phase 3: coalesced streamed writeout
    int ntot = s_ntot;
    for (int i = tid; i < ntot; i += 1024) {
        uint2 r = rec[i];
        int c = r.y >> 16;
        scratch[base_s[c] + (i - lbase[c])] = r;
    }
}

// one block per coarse bucket: fine histogram + scan in LDS, scatter into LDS
// staging, then coalesced writeout. pk_src holds ROW BYTE OFFSETS (src*128).
__global__ void csr_kernel(const uint2* __restrict__ scratch, const int* __restrict__ coarse_base,
                           int* __restrict__ ptr, int* __restrict__ pk_src,
                           unsigned short* __restrict__ pk_val) {
    __shared__ int s[1024];
    __shared__ int fine[256];            // RPB=147 padded
    __shared__ int fill[256];
    __shared__ int lsrc[CAP];            // 35.2 KB
    __shared__ unsigned short lval[CAP]; // 17.6 KB
    int c = blockIdx.x, tid = threadIdx.x;
    int rbeg = c * RPB;
    int rcnt = NR - rbeg;
    if (rcnt > RPB) rcnt = RPB;
    if (rcnt < 0) rcnt = 0;
    int base = coarse_base[c], end = coarse_base[c + 1];
    int n = end - base;
    if (tid < 256) fine[tid] = 0;
    __syncthreads();
    for (int i = tid; i < n; i += 1024)
        atomicAdd(&fine[scratch[base + i].x >> 18], 1);
    __syncthreads();
    int own = (tid < 256) ? fine[tid] : 0;
    s[tid] = own;
    __syncthreads();
    for (int off = 1; off < 256; off <<= 1) {
        int t = (tid >= off) ? s[tid - off] : 0;
        __syncthreads();
        s[tid] += t;
        __syncthreads();
    }
    int excl = s[tid] - own;
    if (tid < rcnt) ptr[rbeg + tid] = base + excl;
    if (tid < 256) fill[tid] = excl;
    __syncthreads();
    if (n <= CAP) {
        for (int i = tid; i < n; i += 1024) {
            uint2 rec = scratch[base + i];
            int dl = rec.x >> 18;
            int slot = atomicAdd(&fill[dl], 1);
            lsrc[slot] = rec.x & 0x3FFFF;
            lval[slot] = (unsigned short)rec.y;
        }
        __syncthreads();
        for (int i = tid; i < n; i += 1024) {
            pk_src[base + i] = lsrc[i] << 7;   // byte offset: src * 128
            pk_val[base + i] = lval[i];
        }
    } else {
        for (int i = tid; i < n; i += 1024) {
            uint2 rec = scratch[base + i];
            int dl = rec.x >> 18;
            int slot = atomicAdd(&fill[dl], 1);
            pk_src[base + slot] = (rec.x & 0x3FFFF) << 7;
            pk_val[base + slot] = (unsigned short)rec.y;
        }
    }
}

// one wave per row; 8 edge-groups x 8 feature-lanes; 32 edges in flight
__global__ void spmm_fused(const int* __restrict__ ptr, const int* __restrict__ pk_src,
                           const _Float16* __restrict__ pk_val,
                           const half8_t* __restrict__ src,
                           half8_t* __restrict__ nexth, float4* __restrict__ out,
                           float final_scale, int store_next) {
    int w = (int)((blockIdx.x * blockDim.x + threadIdx.x) >> 6);
    int lane = threadIdx.x & 63;
    if (w >= NR) return;
    int g = lane >> 3;
    int fl = lane & 7;
    const char* sp = (const char*)src;
    int flo = fl * 16;

    int b = ptr[w], e = ptr[w + 1];
    float acc[8];
#pragma unroll
    for (int k = 0; k < 8; k++) acc[k] = 0.f;

    for (int j = b; j < e; j += 32) {
#pragma unroll
        for (int t = 0; t < 4; t++) {
            int jt = j + 8 * t + g;
            int it = (jt < e) ? jt : b;
            int st = pk_src[it];                       // row byte offset
            float vt = (jt < e) ? (float)pk_val[it] : 0.f;
            half8_t xt = *(const half8_t*)(sp + st + flo);
#pragma unroll
            for (int k = 0; k < 8; k++) acc[k] += vt * (float)xt[k];
        }
    }

#pragma unroll
    for (int k = 0; k < 8; k++) {
        acc[k] += __shfl_xor(acc[k], 8);
        acc[k] += __shfl_xor(acc[k], 16);
        acc[k] += __shfl_xor(acc[k], 32);
    }

    if (lane < 8) {
        float h[8];
#pragma unroll
        for (int k = 0; k < 8; k++) h[k] = 0.5f * acc[k];
        if (store_next) {
            half8_t hh;
#pragma unroll
            for (int k = 0; k < 8; k++) hh[k] = (_Float16)h[k];
            nexth[w * 8 + lane] = hh;
        }
        float4* op = out + (size_t)w * 16 + lane * 2;
        float4 o0 = op[0];
        float4 o1 = op[1];
        o0.x = (o0.x + h[0]) * final_scale;
        o0.y = (o0.y + h[1]) * final_scale;
        o0.z = (o0.z + h[2]) * final_scale;
        o0.w = (o0.w + h[3]) * final_scale;
        o1.x = (o1.x + h[4]) * final_scale;
        o1.y = (o1.y + h[5]) * final_scale;
        o1.z = (o1.z + h[6]) * final_scale;
        o1.w = (o1.w + h[7]) * final_scale;
        op[0] = o0;
        op[1] = o1;
    }
}

extern "C" void kernel_launch(void* const* d_in, const int* in_sizes, int n_in,
                              void* d_out, int out_size, void* d_ws, size_t ws_size,
                              hipStream_t stream) {
    const float* ue      = (const float*)d_in[0];
    const float* ie      = (const float*)d_in[1];
    const float* uu_val  = (const float*)d_in[2];
    const float* ui_val  = (const float*)d_in[3];
    const float* ii_val  = (const float*)d_in[4];
    const int*   uu_rows = (const int*)d_in[5];
    const int*   uu_cols = (const int*)d_in[6];
    const int*   ui_rows = (const int*)d_in[7];
    const int*   ui_cols = (const int*)d_in[8];
    const int*   ii_rows = (const int*)d_in[9];
    const int*   ii_cols = (const int*)d_in[10];

    const int NNZ_UU = in_sizes[2];
    const int NNZ_UI = in_sizes[3];
    const int NNZ_II = in_sizes[4];
    const int NNZT   = 2 * NNZ_UI + NNZ_UU + NNZ_II;
    const int NBLK   = (NNZT + CHUNK - 1) / CHUNK;

    float* out = (float*)d_out;

    // ---- workspace layout (16B-aligned blocks first), ~114 MB total ----
    char* wsb = (char*)d_ws;
    half8_t* curh   = (half8_t*)wsb;                         // NR*128 B = 19.2 MB
    uint2*   scratch = (uint2*)(wsb + (size_t)NR * 128);     // NNZT*8 = 51.2 MB
    half8_t* nexth  = (half8_t*)scratch;                     // aliases scratch (dead after csr)
    int*     pk_src = (int*)(scratch + NNZT);                // NNZT*4
    unsigned short* pk_val = (unsigned short*)(pk_src + NNZT); // NNZT*2
    int*     ptr    = (int*)(pk_val + NNZT);                 // NR+1
    int*     coarse_base = ptr + (NR + 1);                   // COARSE+1
    int*     tots   = coarse_base + (COARSE + 1);            // COARSE
    int*     m      = tots + COARSE;                         // NBLK*COARSE (~4.3 MB)

    init_kernel<<<(NT4 + 255) / 256, 256, 0, stream>>>(
        (const float4*)ue, (const float4*)ie, (float4*)out, (half4_t*)curh);

    count_kernel<<<NBLK, 1024, 0, stream>>>(
        ui_rows, ui_cols, uu_rows, ii_rows, m, NNZ_UI, NNZ_UU, NNZT);

    colsum_kernel<<<COARSE / 128, 128, 0, stream>>>(m, tots, NBLK);
    scan1_kernel<<<1, 1024, 0, stream>>>(tots, coarse_base, ptr + NR);
    rebase_kernel<<<COARSE / 128, 128, 0, stream>>>(m, coarse_base, NBLK);

    place_kernel<<<NBLK, 1024, 0, stream>>>(
        ui_rows, ui_cols, ui_val, uu_rows, uu_cols, uu_val,
        ii_rows, ii_cols, ii_val, m, scratch, NNZ_UI, NNZ_UU, NNZT);

    csr_kernel<<<COARSE, 1024, 0, stream>>>(scratch, coarse_base, ptr, pk_src, pk_val);

    int blocks = (NR * 64 + 511) / 512;   // 8 rows per block

    // layer 1: gather curh -> nexth, out += h
    spmm_fused<<<blocks, 512, 0, stream>>>(
        ptr, pk_src, (const _Float16*)pk_val, curh, nexth, (float4*)out, 1.0f, 1);

    // layer 2: gather nexth, out = (out + h) / 3
    spmm_fused<<<blocks, 512, 0, stream>>>(
        ptr, pk_src, (const _Float16*)pk_val, nexth, curh, (float4*)out, 1.0f / 3.0f, 0);
}

// Round 9
// 515.210 us; speedup vs baseline: 1.4893x; 1.4893x over previous
//
#include <hip/hip_runtime.h>

typedef _Float16 half8_t __attribute__((ext_vector_type(8)));
typedef _Float16 half4_t __attribute__((ext_vector_type(4)));

#define NU 100000
#define NI 50000
#define NR (NU + NI)          // unified rows: users then items
#define D 64
#define COARSE 1024
#define RPB 147               // rows per coarse bucket (147*1024 = 150528 >= NR)
#define CAP 8800              // csr LDS staging capacity (bucket mean 6250, sigma ~79)
#define CHUNK 6144            // placements per block in count/place (fits LDS staging)
#define RPT 6                 // records per thread (CHUNK / 1024)
#define NT4 (NR * 16)         // float4 count of full table

// out = concat(ue, ie) fp32; curh = same data fp16
__global__ void init_kernel(const float4* __restrict__ ue, const float4* __restrict__ ie,
                            float4* __restrict__ out, half4_t* __restrict__ curh) {
    int idx = blockIdx.x * 256 + threadIdx.x;
    if (idx >= NT4) return;
    float4 v = (idx < NU * 16) ? ue[idx] : ie[idx - NU * 16];
    out[idx] = v;
    half4_t h;
    h[0] = (_Float16)v.x; h[1] = (_Float16)v.y; h[2] = (_Float16)v.z; h[3] = (_Float16)v.w;
    curh[idx] = h;
}

// placement p -> dest row (unified row space, items offset by NU)
__device__ __forceinline__ int place_dest(int p, const int* ui_r, const int* ui_c,
                                          const int* uu_r, const int* ii_r,
                                          int n_ui, int n_uu) {
    if (p < 2 * n_ui) {
        int e = p >> 1;
        return (p & 1) ? NU + ui_c[e] : ui_r[e];
    } else if (p < 2 * n_ui + n_uu) {
        return uu_r[p - 2 * n_ui];
    } else {
        return NU + ii_r[p - 2 * n_ui - n_uu];
    }
}

// per-block coarse histogram -> m[block][COARSE]
__global__ void count_kernel(const int* __restrict__ ui_r, const int* __restrict__ ui_c,
                             const int* __restrict__ uu_r, const int* __restrict__ ii_r,
                             int* __restrict__ m, int n_ui, int n_uu, int nnzt) {
    __shared__ int cnt[COARSE];
    int tid = threadIdx.x;
    cnt[tid] = 0;
    __syncthreads();
    int blk0 = blockIdx.x * CHUNK;
#pragma unroll
    for (int k = 0; k < RPT; k++) {
        int p = blk0 + k * 1024 + tid;
        if (p < nnzt) {
            int dest = place_dest(p, ui_r, ui_c, uu_r, ii_r, n_ui, n_uu);
            atomicAdd(&cnt[dest / RPB], 1);
        }
    }
    __syncthreads();
    m[blockIdx.x * COARSE + tid] = cnt[tid];
}

// one block per coarse bucket: parallel column sum of m -> tots[c]
__global__ void colsum_kernel(const int* __restrict__ m, int* __restrict__ tots, int nblk) {
    __shared__ int s[256];
    int c = blockIdx.x, tid = threadIdx.x;
    int sum = 0;
    for (int b = tid; b < nblk; b += 256) sum += m[b * COARSE + c];
    s[tid] = sum;
    __syncthreads();
    for (int off = 128; off > 0; off >>= 1) {
        if (tid < off) s[tid] += s[tid + off];
        __syncthreads();
    }
    if (tid == 0) tots[c] = s[0];
}

// single block: exclusive scan of tots -> coarse_base; set ptr[NR]
__global__ void scan1_kernel(const int* __restrict__ tots, int* __restrict__ coarse_base,
                             int* __restrict__ ptr_nr) {
    __shared__ int s[COARSE];
    int tid = threadIdx.x;
    int x = tots[tid];
    s[tid] = x;
    __syncthreads();
    for (int off = 1; off < COARSE; off <<= 1) {
        int t = (tid >= off) ? s[tid - off] : 0;
        __syncthreads();
        s[tid] += t;
        __syncthreads();
    }
    coarse_base[tid] = s[tid] - x;
    if (tid == COARSE - 1) {
        coarse_base[COARSE] = s[tid];
        *ptr_nr = s[tid];
    }
}

// one block per coarse bucket: segmented exclusive scan down the column,
// rewriting m in place as absolute per-(block,bucket) base offsets.
__global__ void rebase_kernel(int* __restrict__ m, const int* __restrict__ coarse_base, int nblk) {
    __shared__ int s[256];
    int c = blockIdx.x, tid = threadIdx.x;
    int K = (nblk + 255) / 256;
    int b0 = tid * K;
    int b1 = b0 + K;
    if (b1 > nblk) b1 = nblk;
    int sum = 0;
    for (int b = b0; b < b1; b++) sum += m[b * COARSE + c];
    s[tid] = sum;
    __syncthreads();
    for (int off = 1; off < 256; off <<= 1) {
        int t = (tid >= off) ? s[tid - off] : 0;
        __syncthreads();
        s[tid] += t;
        __syncthreads();
    }
    int run = coarse_base[c] + s[tid] - sum;   // exclusive prefix for this thread's range
    for (int b = b0; b < b1; b++) {
        int v = m[b * COARSE + c];
        m[b * COARSE + c] = run;
        run += v;
    }
}

// LDS-staged bucket sort per block -> fully coalesced scratch writeout.
// record: x = dl<<18 | src ; y = (c<<16) | val_fp16  (csr truncates y to 16 bits)
__global__ void place_kernel(const int* __restrict__ ui_r, const int* __restrict__ ui_c,
                             const float* __restrict__ ui_v,
                             const int* __restrict__ uu_r, const int* __restrict__ uu_c,
                             const float* __restrict__ uu_v,
                             const int* __restrict__ ii_r, const int* __restrict__ ii_c,
                             const float* __restrict__ ii_v,
                             const int* __restrict__ m, uint2* __restrict__ scratch,
                             int n_ui, int n_uu, int nnzt) {
    __shared__ uint2 rec[CHUNK];      // 48 KB
    __shared__ int cnt[COARSE];       // 4 KB
    __shared__ int lbase[COARSE];     // 4 KB
    __shared__ int base_s[COARSE];    // 4 KB
    __shared__ int s_ntot;
    int tid = threadIdx.x;
    cnt[tid] = 0;
    __syncthreads();
    int blk0 = blockIdx.x * CHUNK;
    int rk[RPT];
#pragma unroll
    for (int k = 0; k < RPT; k++) {
        int p = blk0 + k * 1024 + tid;
        rk[k] = -1;
        if (p < nnzt) {
            int dest = place_dest(p, ui_r, ui_c, uu_r, ii_r, n_ui, n_uu);
            int c = dest / RPB;
            int lr = atomicAdd(&cnt[c], 1);   // < 6144 -> 14 bits
            rk[k] = (c << 14) | lr;
        }
    }
    __syncthreads();
    // exclusive scan of cnt -> lbase
    int own = cnt[tid];
    lbase[tid] = own;
    __syncthreads();
    for (int off = 1; off < COARSE; off <<= 1) {
        int t = (tid >= off) ? lbase[tid - off] : 0;
        __syncthreads();
        lbase[tid] += t;
        __syncthreads();
    }
    int incl = lbase[tid];
    __syncthreads();
    lbase[tid] = incl - own;
    if (tid == COARSE - 1) s_ntot = incl;
    base_s[tid] = m[blockIdx.x * COARSE + tid];
    __syncthreads();
    // phase 2: decode records, scatter into LDS grouped by bucket
#pragma unroll
    for (int k = 0; k < RPT; k++) {
        int p = blk0 + k * 1024 + tid;
        if (p >= nnzt) continue;
        int dest, src;
        float v;
        if (p < 2 * n_ui) {
            int e = p >> 1;
            int r = ui_r[e], cc = ui_c[e];
            v = ui_v[e];
            if (p & 1) { dest = NU + cc; src = r; }
            else       { dest = r; src = NU + cc; }
        } else if (p < 2 * n_ui + n_uu) {
            int e = p - 2 * n_ui;
            dest = uu_r[e]; src = uu_c[e]; v = uu_v[e];
        } else {
            int e = p - 2 * n_ui - n_uu;
            dest = NU + ii_r[e]; src = NU + ii_c[e]; v = ii_v[e];
        }
        int c  = rk[k] >> 14;
        int lr = rk[k] & 0x3FFF;
        int dl = dest - c * RPB;                  // < 147
        _Float16 hv = (_Float16)v;
        unsigned short us;
        __builtin_memcpy(&us, &hv, 2);
        rec[lbase[c] + lr] = make_uint2(((unsigned)dl << 18) | (unsigned)src,
                                        ((unsigned)c << 16) | (unsigned)us);
    }
    __syncthreads();
    // phase 3: coalesced streamed writeout
    int ntot = s_ntot;
    for (int i = tid; i < ntot; i += 1024) {
        uint2 r = rec[i];
        int c = r.y >> 16;
        scratch[base_s[c] + (i - lbase[c])] = r;
    }
}

// one block per coarse bucket: fine histogram + scan in LDS, scatter into LDS
// staging, then coalesced writeout. pk_src holds ROW BYTE OFFSETS (src*128).
__global__ void csr_kernel(const uint2* __restrict__ scratch, const int* __restrict__ coarse_base,
                           int* __restrict__ ptr, int* __restrict__ pk_src,
                           unsigned short* __restrict__ pk_val) {
    __shared__ int s[1024];
    __shared__ int fine[256];            // RPB=147 padded
    __shared__ int fill[256];
    __shared__ int lsrc[CAP];            // 35.2 KB
    __shared__ unsigned short lval[CAP]; // 17.6 KB
    int c = blockIdx.x, tid = threadIdx.x;
    int rbeg = c * RPB;
    int rcnt = NR - rbeg;
    if (rcnt > RPB) rcnt = RPB;
    if (rcnt < 0) rcnt = 0;
    int base = coarse_base[c], end = coarse_base[c + 1];
    int n = end - base;
    if (tid < 256) fine[tid] = 0;
    __syncthreads();
    for (int i = tid; i < n; i += 1024)
        atomicAdd(&fine[scratch[base + i].x >> 18], 1);
    __syncthreads();
    int own = (tid < 256) ? fine[tid] : 0;
    s[tid] = own;
    __syncthreads();
    for (int off = 1; off < 256; off <<= 1) {
        int t = (tid >= off) ? s[tid - off] : 0;
        __syncthreads();
        s[tid] += t;
        __syncthreads();
    }
    int excl = s[tid] - own;
    if (tid < rcnt) ptr[rbeg + tid] = base + excl;
    if (tid < 256) fill[tid] = excl;
    __syncthreads();
    if (n <= CAP) {
        for (int i = tid; i < n; i += 1024) {
            uint2 rec = scratch[base + i];
            int dl = rec.x >> 18;
            int slot = atomicAdd(&fill[dl], 1);
            lsrc[slot] = rec.x & 0x3FFFF;
            lval[slot] = (unsigned short)rec.y;
        }
        __syncthreads();
        for (int i = tid; i < n; i += 1024) {
            pk_src[base + i] = lsrc[i] << 7;   // byte offset: src * 128
            pk_val[base + i] = lval[i];
        }
    } else {
        for (int i = tid; i < n; i += 1024) {
            uint2 rec = scratch[base + i];
            int dl = rec.x >> 18;
            int slot = atomicAdd(&fill[dl], 1);
            pk_src[base + slot] = (rec.x & 0x3FFFF) << 7;
            pk_val[base + slot] = (unsigned short)rec.y;
        }
    }
}

// one wave per row; 8 edge-groups x 8 feature-lanes; 32 edges in flight
__global__ void spmm_fused(const int* __restrict__ ptr, const int* __restrict__ pk_src,
                           const _Float16* __restrict__ pk_val,
                           const half8_t* __restrict__ src,
                           half8_t* __restrict__ nexth, float4* __restrict__ out,
                           float final_scale, int store_next) {
    int w = (int)((blockIdx.x * blockDim.x + threadIdx.x) >> 6);
    int lane = threadIdx.x & 63;
    if (w >= NR) return;
    int g = lane >> 3;
    int fl = lane & 7;
    const char* sp = (const char*)src;
    int flo = fl * 16;

    int b = ptr[w], e = ptr[w + 1];
    float acc[8];
#pragma unroll
    for (int k = 0; k < 8; k++) acc[k] = 0.f;

    for (int j = b; j < e; j += 32) {
#pragma unroll
        for (int t = 0; t < 4; t++) {
            int jt = j + 8 * t + g;
            int it = (jt < e) ? jt : b;
            int st = pk_src[it];                       // row byte offset
            float vt = (jt < e) ? (float)pk_val[it] : 0.f;
            half8_t xt = *(const half8_t*)(sp + st + flo);
#pragma unroll
            for (int k = 0; k < 8; k++) acc[k] += vt * (float)xt[k];
        }
    }

#pragma unroll
    for (int k = 0; k < 8; k++) {
        acc[k] += __shfl_xor(acc[k], 8);
        acc[k] += __shfl_xor(acc[k], 16);
        acc[k] += __shfl_xor(acc[k], 32);
    }

    if (lane < 8) {
        float h[8];
#pragma unroll
        for (int k = 0; k < 8; k++) h[k] = 0.5f * acc[k];
        if (store_next) {
            half8_t hh;
#pragma unroll
            for (int k = 0; k < 8; k++) hh[k] = (_Float16)h[k];
            nexth[w * 8 + lane] = hh;
        }
        float4* op = out + (size_t)w * 16 + lane * 2;
        float4 o0 = op[0];
        float4 o1 = op[1];
        o0.x = (o0.x + h[0]) * final_scale;
        o0.y = (o0.y + h[1]) * final_scale;
        o0.z = (o0.z + h[2]) * final_scale;
        o0.w = (o0.w + h[3]) * final_scale;
        o1.x = (o1.x + h[4]) * final_scale;
        o1.y = (o1.y + h[5]) * final_scale;
        o1.z = (o1.z + h[6]) * final_scale;
        o1.w = (o1.w + h[7]) * final_scale;
        op[0] = o0;
        op[1] = o1;
    }
}

extern "C" void kernel_launch(void* const* d_in, const int* in_sizes, int n_in,
                              void* d_out, int out_size, void* d_ws, size_t ws_size,
                              hipStream_t stream) {
    const float* ue      = (const float*)d_in[0];
    const float* ie      = (const float*)d_in[1];
    const float* uu_val  = (const float*)d_in[2];
    const float* ui_val  = (const float*)d_in[3];
    const float* ii_val  = (const float*)d_in[4];
    const int*   uu_rows = (const int*)d_in[5];
    const int*   uu_cols = (const int*)d_in[6];
    const int*   ui_rows = (const int*)d_in[7];
    const int*   ui_cols = (const int*)d_in[8];
    const int*   ii_rows = (const int*)d_in[9];
    const int*   ii_cols = (const int*)d_in[10];

    const int NNZ_UU = in_sizes[2];
    const int NNZ_UI = in_sizes[3];
    const int NNZ_II = in_sizes[4];
    const int NNZT   = 2 * NNZ_UI + NNZ_UU + NNZ_II;
    const int NBLK   = (NNZT + CHUNK - 1) / CHUNK;

    float* out = (float*)d_out;

    // ---- workspace layout (16B-aligned blocks first), ~114 MB total ----
    char* wsb = (char*)d_ws;
    half8_t* curh   = (half8_t*)wsb;                         // NR*128 B = 19.2 MB
    uint2*   scratch = (uint2*)(wsb + (size_t)NR * 128);     // NNZT*8 = 51.2 MB
    half8_t* nexth  = (half8_t*)scratch;                     // aliases scratch (dead after csr)
    int*     pk_src = (int*)(scratch + NNZT);                // NNZT*4
    unsigned short* pk_val = (unsigned short*)(pk_src + NNZT); // NNZT*2
    int*     ptr    = (int*)(pk_val + NNZT);                 // NR+1
    int*     coarse_base = ptr + (NR + 1);                   // COARSE+1
    int*     tots   = coarse_base + (COARSE + 1);            // COARSE
    int*     m      = tots + COARSE;                         // NBLK*COARSE (~4.3 MB)

    init_kernel<<<(NT4 + 255) / 256, 256, 0, stream>>>(
        (const float4*)ue, (const float4*)ie, (float4*)out, (half4_t*)curh);

    count_kernel<<<NBLK, 1024, 0, stream>>>(
        ui_rows, ui_cols, uu_rows, ii_rows, m, NNZ_UI, NNZ_UU, NNZT);

    colsum_kernel<<<COARSE, 256, 0, stream>>>(m, tots, NBLK);
    scan1_kernel<<<1, 1024, 0, stream>>>(tots, coarse_base, ptr + NR);
    rebase_kernel<<<COARSE, 256, 0, stream>>>(m, coarse_base, NBLK);

    place_kernel<<<NBLK, 1024, 0, stream>>>(
        ui_rows, ui_cols, ui_val, uu_rows, uu_cols, uu_val,
        ii_rows, ii_cols, ii_val, m, scratch, NNZ_UI, NNZ_UU, NNZT);

    csr_kernel<<<COARSE, 1024, 0, stream>>>(scratch, coarse_base, ptr, pk_src, pk_val);

    int blocks = (NR * 64 + 511) / 512;   // 8 rows per block

    // layer 1: gather curh -> nexth, out += h
    spmm_fused<<<blocks, 512, 0, stream>>>(
        ptr, pk_src, (const _Float16*)pk_val, curh, nexth, (float4*)out, 1.0f, 1);

    // layer 2: gather nexth, out = (out + h) / 3
    spmm_fused<<<blocks, 512, 0, stream>>>(
        ptr, pk_src, (const _Float16*)pk_val, nexth, curh, (float4*)out, 1.0f / 3.0f, 0);
}